// Round 10
// baseline (149.791 us; speedup 1.0000x reference)
//
#include <hip/hip_runtime.h>

#define IMG_W 512
#define IMG_H 512
#define N_IMG 48            // 16 batch * 3 channels
#define TILE_W 64
#define TILE_H 32           // R13: keep 32 (R12's 16 was +75% dur).
#define RAD 5
#define NBX (IMG_W / TILE_W)   // 8
#define NBY (IMG_H / TILE_H)   // 16

typedef float f32x4v __attribute__((ext_vector_type(4)));
typedef short bf16x8 __attribute__((ext_vector_type(8)));

// R16: fp32x2 -> packed bf16x2 in 3 VALU ops (2 adds + v_perm_b32).
// Round-half-up: same 0.5-ulp bound as RNE. All packed values finite
// non-negative (<~1.2) so +0x8000 can't carry into inf/NaN. No inline asm.
__device__ inline unsigned int bf16pair(float a, float b) {
    const unsigned int ua = __float_as_uint(a) + 0x8000u;
    const unsigned int ub = __float_as_uint(b) + 0x8000u;
    return __builtin_amdgcn_perm(ub, ua, 0x07060302u);
}

// Scalar RNE (make_frag only — off the hot path).
__device__ inline short bf16r(float a) {
    unsigned int u = __float_as_uint(a);
    u = (u + 0x7fffu + ((u >> 16) & 1u)) >> 16;
    return (short)u;
}

// R10/R11: fragment build via closed form (no ssum loop, no divide):
//   w(d) = exp2(-(d-5)^2 * log2e/4.5) * (1/ssum), constants folded.
__device__ inline bf16x8 make_frag(int dbase) {
    bf16x8 f;
    #pragma unroll
    for (int j = 0; j < 8; ++j) {
        const int d = dbase + j;
        const float x = (float)(d - 5);
        const float w = exp2f(-0.32059890f * x * x) * 0.26601246f;
        f[j] = bf16r((d >= 0 && d <= 10) ? w : 0.f);
    }
    return f;
}

// R15: acc is up to 64 slots, each on its own 64B cache line.
__global__ void ssim_zero_acc(double* acc, int slotmask) {
    const int i = threadIdx.x;
    if (i <= slotmask) acc[i * 8] = 0.0;
}

// NOTE 1 (R3/R4 vs R5): NO __threadfence / fold-in finalize.
// NOTE 2 (R8): both 11-tap convs on MFMA; banded Gaussian weights in B.
// NOTE 3 (R14): pass1->pass2 is an in-wave shuffle transpose.
// NOTE 4 (R15): atomic spread over 64 cache lines (-33 us).
// NOTE 5 (R16): perm-based 3-op bf16 pack (-7 us).
// NOTE 6 (R17): pp/tt/pt derived in-register (elementwise in p,t) (-5 us).
// NOTE 7 (R18): staging LDS DELETED. Each lane loads its own fragment window
// directly from global: cols cbase=col0+wv*16+8q-8 (always ==0 mod 8, and
// IMG_W%8==0 -> every 8-col group fully in or fully out of the image: a
// single per-lane predicate, zeros if OOB; no partial/scalar edge path).
// Removes the staging phase, all staging LDS traffic, and the only compute
// barrier — waves are independent start to finish. Extra inter-wave halo
// re-reads (~1.6x L2 traffic) are absorbed by L2/L3; HBM FETCH ~flat.
// pp/tt/pt pack directly from loaded f32 (bf16(p*t): tighter than R17's
// bf16(bf16p*bf16t)).
__global__ __launch_bounds__(256, 6)
void ssim_main(const float* __restrict__ pred, const float* __restrict__ targ,
               double* __restrict__ acc, int slotmask)
{
    __shared__ float wave_part[4];

    const int tid  = threadIdx.x;
    const int lane = tid & 63;
    const int wv   = tid >> 6;     // wave 0..3
    const int n15  = lane & 15;
    const int q    = lane >> 4;    // 0..3

    const int col0 = blockIdx.x * TILE_W;
    const int row0 = blockIdx.y * TILE_H;
    const long img = blockIdx.z;
    const float* __restrict__ p = pred + img * (long)(IMG_H * IMG_W);
    const float* __restrict__ t = targ + img * (long)(IMG_H * IMG_W);

    // ---- Direct fragment loads: 3 m-tiles x {p,t} x 2 float4 (R18).
    const int cbase = col0 + wv * 16 + 8 * q - 8;           // 8-col group start
    const bool colok = (cbase >= 0) && (cbase <= IMG_W - 8); // whole group in/out
    float4 Pl[3], Ph[3], Tl[3], Th[3];
    #pragma unroll
    for (int mt = 0; mt < 3; ++mt) {
        const float4 z = {0.f, 0.f, 0.f, 0.f};
        Pl[mt] = z; Ph[mt] = z; Tl[mt] = z; Th[mt] = z;
        const int gr = row0 - RAD + mt * 16 + n15;
        if (colok && gr >= 0 && gr < IMG_H) {
            const float* __restrict__ prow = p + (long)gr * IMG_W + cbase;
            const float* __restrict__ trow = t + (long)gr * IMG_W + cbase;
            Pl[mt] = *(const float4*)prow;
            Ph[mt] = *(const float4*)(prow + 4);
            Tl[mt] = *(const float4*)trow;
            Th[mt] = *(const float4*)(trow + 4);
        }
    }

    // B fragments — independent VALU work between load issue and use.
    const bf16x8 Bh = make_frag(q * 8 - n15 - 3);
    const bf16x8 Bv = make_frag(q * 8 - n15);

    // ---- MFMA pass 1: horizontal conv, 5 arrays from the loaded f32s.
    // A[m][k] = X[mt*16+m][wv*16+k] (X = bf16 image window, built here in
    // registers). D: lane (q,n) gets rows q*4+{0..3} of col n -> yreg.
    uint2 yreg[15];
    {
        const f32x4v cz = {0.f, 0.f, 0.f, 0.f};
        #pragma unroll
        for (int mt = 0; mt < 3; ++mt) {
            const float pf[8] = {Pl[mt].x, Pl[mt].y, Pl[mt].z, Pl[mt].w,
                                 Ph[mt].x, Ph[mt].y, Ph[mt].z, Ph[mt].w};
            const float tf[8] = {Tl[mt].x, Tl[mt].y, Tl[mt].z, Tl[mt].w,
                                 Th[mt].x, Th[mt].y, Th[mt].z, Th[mt].w};
            unsigned int pd[4], td[4], ppd[4], ttd[4], ptd[4];
            #pragma unroll
            for (int j = 0; j < 4; ++j) {
                const float a = pf[2 * j], b = pf[2 * j + 1];
                const float c = tf[2 * j], d = tf[2 * j + 1];
                pd[j]  = bf16pair(a, b);
                td[j]  = bf16pair(c, d);
                ppd[j] = bf16pair(a * a, b * b);
                ttd[j] = bf16pair(c * c, d * d);
                ptd[j] = bf16pair(a * c, b * d);
            }
            union U { unsigned int u[4]; bf16x8 f; };
            const U Ap  = {{pd[0], pd[1], pd[2], pd[3]}};
            const U At  = {{td[0], td[1], td[2], td[3]}};
            const U App = {{ppd[0], ppd[1], ppd[2], ppd[3]}};
            const U Att = {{ttd[0], ttd[1], ttd[2], ttd[3]}};
            const U Apt = {{ptd[0], ptd[1], ptd[2], ptd[3]}};
            const f32x4v c0v = __builtin_amdgcn_mfma_f32_16x16x32_bf16(Ap.f,  Bh, cz, 0, 0, 0);
            const f32x4v c1v = __builtin_amdgcn_mfma_f32_16x16x32_bf16(At.f,  Bh, cz, 0, 0, 0);
            const f32x4v c2v = __builtin_amdgcn_mfma_f32_16x16x32_bf16(App.f, Bh, cz, 0, 0, 0);
            const f32x4v c3v = __builtin_amdgcn_mfma_f32_16x16x32_bf16(Att.f, Bh, cz, 0, 0, 0);
            const f32x4v c4v = __builtin_amdgcn_mfma_f32_16x16x32_bf16(Apt.f, Bh, cz, 0, 0, 0);
            yreg[0 * 3 + mt] = make_uint2(bf16pair(c0v[0], c0v[1]), bf16pair(c0v[2], c0v[3]));
            yreg[1 * 3 + mt] = make_uint2(bf16pair(c1v[0], c1v[1]), bf16pair(c1v[2], c1v[3]));
            yreg[2 * 3 + mt] = make_uint2(bf16pair(c2v[0], c2v[1]), bf16pair(c2v[2], c2v[3]));
            yreg[3 * 3 + mt] = make_uint2(bf16pair(c3v[0], c3v[1]), bf16pair(c3v[2], c3v[3]));
            yreg[4 * 3 + mt] = make_uint2(bf16pair(c4v[0], c4v[1]), bf16pair(c4v[2], c4v[3]));
        }
    }

    // ---- Pass 1 -> pass 2 hand-off: in-wave transpose via shuffles (R14).
    // Lane (q,n) needs Y rows nt*16+8q+{0..7} of col n = dwords of lanes
    // srcA=((q&1)<<5)+n and srcB=srcA+16, from row-tile mt = nt + (q>>1).
    const int srcA = ((q & 1) << 5) + n15;
    const int srcB = srcA + 16;
    const bool hi = (q >= 2);

    // ---- MFMA pass 2: vertical conv, fragments from shuffles.
    f32x4v accv[2][5];
    {
        const f32x4v cz = {0.f, 0.f, 0.f, 0.f};
        #pragma unroll
        for (int a = 0; a < 5; ++a) {
            int sA0[3], sA1[3], sB0[3], sB1[3];
            #pragma unroll
            for (int mt = 0; mt < 3; ++mt) {
                const uint2 y = yreg[a * 3 + mt];
                sA0[mt] = __shfl((int)y.x, srcA, 64);
                sA1[mt] = __shfl((int)y.y, srcA, 64);
                sB0[mt] = __shfl((int)y.x, srcB, 64);
                sB1[mt] = __shfl((int)y.y, srcB, 64);
            }
            #pragma unroll
            for (int nt = 0; nt < 2; ++nt) {
                union { int u[4]; bf16x8 f; } A;
                A.u[0] = hi ? sA0[nt + 1] : sA0[nt];
                A.u[1] = hi ? sA1[nt + 1] : sA1[nt];
                A.u[2] = hi ? sB0[nt + 1] : sB0[nt];
                A.u[3] = hi ? sB1[nt + 1] : sB1[nt];
                accv[nt][a] = __builtin_amdgcn_mfma_f32_16x16x32_bf16(A.f, Bv, cz, 0, 0, 0);
            }
        }
    }

    // ---- SSIM on 8 pixels/lane (2 n-tiles x 4 cols), fp32 ----
    float lsum = 0.f;
    #pragma unroll
    for (int nt = 0; nt < 2; ++nt) {
        const f32x4v m1 = accv[nt][0], m2 = accv[nt][1];
        const f32x4v epp = accv[nt][2], ett = accv[nt][3], ept = accv[nt][4];
        const f32x4v m1s = m1 * m1, m2s = m2 * m2, m12 = m1 * m2;
        const f32x4v num = (2.f * m12 + 1e-4f) * (2.f * (ept - m12) + 9e-4f);
        const f32x4v den = (m1s + m2s + 1e-4f) * ((epp - m1s) + (ett - m2s) + 9e-4f);
        lsum += num[0] * __builtin_amdgcn_rcpf(den[0]);
        lsum += num[1] * __builtin_amdgcn_rcpf(den[1]);
        lsum += num[2] * __builtin_amdgcn_rcpf(den[2]);
        lsum += num[3] * __builtin_amdgcn_rcpf(den[3]);
    }

    // ---- Block reduction -> one double atomic per block, 64 slots (R15) ----
    #pragma unroll
    for (int off = 32; off > 0; off >>= 1)
        lsum += __shfl_down(lsum, off, 64);
    if (lane == 0) wave_part[wv] = lsum;
    __syncthreads();
    if (tid == 0) {
        const float bs = wave_part[0] + wave_part[1] + wave_part[2] + wave_part[3];
        const int lid = blockIdx.x + NBX * (blockIdx.y + NBY * (int)blockIdx.z);
        atomicAdd(acc + (lid & slotmask) * 8, (double)bs);
    }
}

__global__ void ssim_final(const double* __restrict__ acc, float* __restrict__ out,
                           int slotmask) {
    if (threadIdx.x == 0) {
        double s = 0.0;
        for (int i = 0; i <= slotmask; ++i) s += acc[i * 8];
        const double n = (double)N_IMG * (double)IMG_H * (double)IMG_W;
        out[0] = (float)(1.0 - s / n);
    }
}

extern "C" void kernel_launch(void* const* d_in, const int* in_sizes, int n_in,
                              void* d_out, int out_size, void* d_ws, size_t ws_size,
                              hipStream_t stream) {
    const float* pred = (const float*)d_in[0];
    const float* targ = (const float*)d_in[1];
    float* out  = (float*)d_out;
    double* acc = (double*)d_ws;

    // R15: 64 atomic slots, 64B apart (4KB) when ws allows; else legacy 1 slot.
    const int nslots = (ws_size >= (size_t)(64 * 64)) ? 64 : 1;
    const int slotmask = nslots - 1;

    hipLaunchKernelGGL(ssim_zero_acc, dim3(1), dim3(64), 0, stream, acc, slotmask);
    dim3 grid(NBX, NBY, N_IMG);   // (8, 16, 48)
    hipLaunchKernelGGL(ssim_main, grid, dim3(256), 0, stream, pred, targ, acc, slotmask);
    hipLaunchKernelGGL(ssim_final, dim3(1), dim3(1), 0, stream, acc, out, slotmask);
}